// Round 12
// baseline (176.470 us; speedup 1.0000x reference)
//
#include <hip/hip_runtime.h>
#include <hip/hip_bf16.h>
#include <hip/hip_fp8.h>
#include <cstdint>
#include <cstddef>

// out = where(min_dist(x, cache_emb) <= 0.01, cache_out[argmin], x@W+b)
// N=8192, M=16384, D=512, K=512, f32 in/out.
// gemm_min: non-scaled fp8 e4m3, 128x256 tile, 8 waves (2x4), kt-blocked
//   global layout, row-pair XOR swizzle (0 conflicts, R10/R11-verified),
//   double-buffered BK=64 pipeline, counted vmcnt(3), 2 blocks/CU.
// gemm_out: bf16 (accuracy), unchanged.

#define NQ 8192
#define MC 16384
#define DD 512
#define KK 512

typedef float f32x4 __attribute__((ext_vector_type(4)));
typedef __bf16 bf16x8 __attribute__((ext_vector_type(8)));
typedef short short8 __attribute__((ext_vector_type(8)));

// ---- workspace layout (bytes) ----
#define MIN_OFF 0u
#define X2_OFF 65536u
#define C2_OFF 98304u
#define XB_OFF 163840u                          // bf16 x: 8 MB
#define XQ_OFF (XB_OFF + 8388608u)              // fp8 x (blocked, 128-panels): 4 MB
#define CQ_OFF (XQ_OFF + 4194304u)              // fp8 cache_emb (blocked, 256-panels): 8 MB
#define WT_OFF (CQ_OFF + 8388608u)              // bf16 W^T: 512 KB
#define PART_OFF (WT_OFF + 524288u)             // partial mins: 4 MB

__device__ __forceinline__ short f2bf(float f) {
  unsigned int u = __float_as_uint(f);
  u += 0x7FFFu + ((u >> 16) & 1u);
  return (short)(u >> 16);
}

__device__ __forceinline__ void gload_lds16(const void* g, void* l) {
  __builtin_amdgcn_global_load_lds(
      (__attribute__((address_space(1))) void*)(g),
      (__attribute__((address_space(3))) void*)(l), 16, 0, 0);
}

__device__ __forceinline__ unsigned long long u64min(unsigned long long a,
                                                     unsigned long long b) {
  return a < b ? a : b;
}

// ---- cast rows to fp8 (kt-blocked layout, panel of 2^PS rows) ----
// tile (panel=row>>PS, kt) is (2^PS * 64) B contiguous; row rl within it
// occupies 64 B; 8B group gl stored at gl ^ ((rl>>1)&7)  [row-pair swizzle].
template <int WRITE_BF16, int PS>
__global__ __launch_bounds__(256) void prep_rows(const float* __restrict__ src,
                                                 short* __restrict__ dstb,
                                                 unsigned char* __restrict__ dstq,
                                                 float* __restrict__ dst2) {
  const int lane = threadIdx.x & 63;
  const size_t row = (size_t)blockIdx.x * 4 + (threadIdx.x >> 6);
  const float4* p = (const float4*)(src + row * DD + lane * 8);
  float4 v0 = p[0], v1 = p[1];
  float v[8] = {v0.x, v0.y, v0.z, v0.w, v1.x, v1.y, v1.z, v1.w};
  unsigned long long pk = 0;
  float s = 0.f;
#pragma unroll
  for (int j = 0; j < 8; ++j) {
    __hip_fp8_e4m3 q(v[j]);
    float qf = (float)q;
    s += qf * qf;
    pk |= (unsigned long long)q.__x << (8 * j);
  }
  const int kt = lane >> 3, gl = lane & 7;
  const int rl = (int)row & ((1 << PS) - 1);
  const size_t panel = row >> PS;
  const size_t tile_bytes = (size_t)(1 << PS) * 64;
  *(unsigned long long*)(dstq + (panel * 8 + kt) * tile_bytes + rl * 64 +
                         ((gl ^ ((rl >> 1) & 7)) << 3)) = pk;
  if (WRITE_BF16) {
    short8 o;
#pragma unroll
    for (int j = 0; j < 8; ++j) o[j] = f2bf(v[j]);
    *(short8*)(dstb + row * DD + lane * 8) = o;
  }
#pragma unroll
  for (int m = 32; m >= 1; m >>= 1) s += __shfl_xor(s, m, 64);
  if (lane == 0) dst2[row] = s;
}

// ---- transpose-cast W[d][j] -> wt[j][d] (bf16) ----
__global__ __launch_bounds__(256) void prep_w(const float* __restrict__ W,
                                              short* __restrict__ wt) {
  __shared__ float t[64][65];
  const int bx = blockIdx.x, by = blockIdx.y;
#pragma unroll
  for (int i = 0; i < 16; ++i) {
    int idx = i * 256 + threadIdx.x;
    int r = idx >> 6, c = idx & 63;
    t[r][c] = W[(size_t)(by * 64 + r) * KK + bx * 64 + c];
  }
  __syncthreads();
#pragma unroll
  for (int i = 0; i < 16; ++i) {
    int idx = i * 256 + threadIdx.x;
    int r = idx >> 6, c = idx & 63;
    wt[(size_t)(bx * 64 + r) * DD + by * 64 + c] = f2bf(t[c][r]);
  }
}

// ======================= fp8 distance GEMM (pipelined) =======================
// 128x256 tile, 8 waves (2 row x 4 col of 64x64). Double-buffered BK=64:
// per kt { STAGE(kt+1): 3 gloads/thread ; vmcnt(3) ; barrier ;
// ds_read+MFMA(kt) ; barrier }. Frag slot (ks*4+cr)^((cl>>1)&7) -> 2-way
// bank alias (free; R10/R11 measured 0 conflicts).
__global__ __launch_bounds__(512, 4) void gemm_min(
    const unsigned char* __restrict__ xq, const unsigned char* __restrict__ cq,
    const float* __restrict__ x2, const float* __restrict__ c2,
    unsigned long long* __restrict__ part) {
  __shared__ unsigned char LA[2][8192];   // A: 128 x 64B
  __shared__ unsigned char LB[2][16384];  // B: 256 x 64B   (48 KiB total)
  const int tid = threadIdx.x;
  const int lane = tid & 63;
  const int wid = tid >> 6;
  const int wr = wid >> 2, wc = wid & 3;  // 2x4 wave grid, 64x64 each
  const int cl = lane & 15, cr = lane >> 4;

  // XCD mapping: per XCD 8 fixed A-panels; B walked in groups of 16.
  const int bid = blockIdx.x;                 // 0..4095
  const int xcd = bid & 7;
  const int k = bid >> 3;                     // 0..511
  const int by = xcd * 8 + ((k >> 4) & 7);    // 0..63 (128-row A panels)
  const int bx = ((k >> 7) << 4) | (k & 15);  // 0..63 (256-row B panels)
  const size_t row0 = (size_t)by * 128;
  const size_t col0 = (size_t)bx * 256;

  const unsigned char* tA = xq + (size_t)by * 65536;   // 8 tiles x 8192 B
  const unsigned char* tB = cq + (size_t)bx * 131072;  // 8 tiles x 16384 B

  f32x4 acc[4][4];
#pragma unroll
  for (int m = 0; m < 4; ++m)
#pragma unroll
    for (int n = 0; n < 4; ++n) acc[m][n] = (f32x4)0.0f;

#define STAGE(buf, kt)                                                   \
  do {                                                                   \
    gload_lds16(tA + (kt) * 8192 + tid * 16, &LA[buf][tid * 16]);        \
    gload_lds16(tB + (kt) * 16384 + tid * 16, &LB[buf][tid * 16]);       \
    gload_lds16(tB + (kt) * 16384 + 8192 + tid * 16,                     \
                &LB[buf][8192 + tid * 16]);                              \
  } while (0)

  int cur = 0;
  STAGE(0, 0);  // 3 loads in flight
  for (int kt = 0; kt < 8; ++kt) {
    if (kt < 7) {
      STAGE(cur ^ 1, kt + 1);  // issue next tile (6 in flight)
      asm volatile("s_waitcnt vmcnt(3)" ::: "memory");  // cur's 3 done
    } else {
      asm volatile("s_waitcnt vmcnt(0)" ::: "memory");
    }
    __builtin_amdgcn_s_barrier();        // all waves: cur staged
    __builtin_amdgcn_sched_barrier(0);   // pin ds_reads below (rule #18)
    const unsigned char* lAr = &LA[cur][(wr * 64 + cl) * 64];
    const unsigned char* lBr = &LB[cur][(wc * 64 + cl) * 64];
#pragma unroll
    for (int ks = 0; ks < 2; ++ks) {
      const int sl = ((ks * 4 + cr) ^ ((cl >> 1) & 7)) << 3;
      long a[4], b[4];
#pragma unroll
      for (int m = 0; m < 4; ++m) a[m] = *(const long*)(lAr + m * 1024 + sl);
#pragma unroll
      for (int n = 0; n < 4; ++n) b[n] = *(const long*)(lBr + n * 1024 + sl);
#pragma unroll
      for (int m = 0; m < 4; ++m)
#pragma unroll
        for (int n = 0; n < 4; ++n)
          acc[m][n] = __builtin_amdgcn_mfma_f32_16x16x32_fp8_fp8(
              a[m], b[n], acc[m][n], 0, 0, 0);
    }
    __builtin_amdgcn_s_barrier();  // all waves done reading cur ->
    cur ^= 1;                      // next iter may overwrite it
  }
#undef STAGE

  // epilogue: d2 = x2 + c2 - 2S; pack (d2bits,col); 16-lane butterfly;
  // cross-wave LDS combine (4 col-waves); one atomicMin per row per block.
  unsigned long long* ls = (unsigned long long*)&LA[0][0];  // [128][4]
  float c2v[4];
#pragma unroll
  for (int n = 0; n < 4; ++n) c2v[n] = c2[col0 + wc * 64 + n * 16 + cl];
#pragma unroll
  for (int m = 0; m < 4; ++m) {
#pragma unroll
    for (int r = 0; r < 4; ++r) {
      const int row_local = wr * 64 + m * 16 + cr * 4 + r;
      const float xv = x2[row0 + row_local];
      unsigned long long best = ~0ull;
#pragma unroll
      for (int n = 0; n < 4; ++n) {
        float d2 = fmaxf(xv + c2v[n] - 2.0f * acc[m][n][r], 0.0f);
        unsigned int col = (unsigned int)(col0 + wc * 64 + n * 16 + cl);
        unsigned long long key =
            ((unsigned long long)__float_as_uint(d2) << 32) | col;
        best = u64min(best, key);
      }
#pragma unroll
      for (int msk = 8; msk >= 1; msk >>= 1) {
        unsigned long long o = __shfl_xor(best, msk, 64);
        best = u64min(best, o);
      }
      if (cl == 0) ls[row_local * 4 + wc] = best;
    }
  }
  __syncthreads();
  if (tid < 128) {
    unsigned long long b = u64min(u64min(ls[tid * 4 + 0], ls[tid * 4 + 1]),
                                  u64min(ls[tid * 4 + 2], ls[tid * 4 + 3]));
    atomicMin(&part[(size_t)(row0 + tid) * 64 + bx], b);
  }
}

// ---- final argmin reduce ----
__global__ __launch_bounds__(256) void reduce_mink(
    const unsigned long long* __restrict__ part,
    unsigned long long* __restrict__ mink) {
  const int row = blockIdx.x * 256 + threadIdx.x;
  const unsigned long long* p = part + (size_t)row * 64;
  unsigned long long best = ~0ull;
#pragma unroll
  for (int j = 0; j < 64; ++j) best = best < p[j] ? best : p[j];
  mink[row] = best;
}

// ======================= bf16 fallback GEMM (unchanged) ======================
__device__ __forceinline__ void stage_offs(unsigned go[4], size_t grow0,
                                           int wid, int lane) {
#pragma unroll
  for (int j = 0; j < 4; ++j) {
    const int ch = wid * 256 + j * 64 + lane;
    const int r = ch >> 3;
    const int c = (ch & 7) ^ (r & 7);
    go[j] = (unsigned)((grow0 + (size_t)r) * (DD * 2) + c * 16);
  }
}

__device__ __forceinline__ void stage_tile(const char* base,
                                           const unsigned go[4], unsigned kb,
                                           char* lds, int wid) {
#pragma unroll
  for (int j = 0; j < 4; ++j)
    gload_lds16(base + go[j] + kb, lds + (wid * 256 + j * 64) * 16);
}

__device__ __forceinline__ bf16x8 ld_frag(const short* lrow0, int m, int ks,
                                          int cr, int cl) {
  const int slot = (ks * 4 + cr) ^ (cl & 7);
  return *(const bf16x8*)(lrow0 + m * 16 * 64 + slot * 8);
}

__global__ __launch_bounds__(256, 3) void gemm_out(
    const short* __restrict__ xb, const short* __restrict__ wt,
    const float* __restrict__ bias, const float* __restrict__ cache_out,
    const unsigned long long* __restrict__ mink, float* __restrict__ out) {
  __shared__ short lA[128 * 64];
  __shared__ short lB[128 * 64];
  const int tid = threadIdx.x;
  const int lane = tid & 63;
  const int wid = tid >> 6;
  const int wr = wid >> 1, wc = wid & 1;
  const int cl = lane & 15, cr = lane >> 4;
  const size_t row0 = (size_t)blockIdx.y * 128;
  const size_t col0 = (size_t)blockIdx.x * 128;

  unsigned goA[4], goB[4];
  stage_offs(goA, row0, wid, lane);
  stage_offs(goB, col0, wid, lane);
  const char* xbp = (const char*)xb;
  const char* wtp = (const char*)wt;

  f32x4 acc[4][4];
#pragma unroll
  for (int m = 0; m < 4; ++m)
#pragma unroll
    for (int n = 0; n < 4; ++n) acc[m][n] = (f32x4)0.0f;

  const short* lArow = lA + (wr * 64 + cl) * 64;
  const short* lBrow = lB + (wc * 64 + cl) * 64;

  for (int kt = 0; kt < DD / 64; ++kt) {
    stage_tile(xbp, goA, (unsigned)kt * 128, (char*)lA, wid);
    stage_tile(wtp, goB, (unsigned)kt * 128, (char*)lB, wid);
    __syncthreads();
#pragma unroll
    for (int ks = 0; ks < 2; ++ks) {
      bf16x8 a[4], b[4];
#pragma unroll
      for (int m = 0; m < 4; ++m) a[m] = ld_frag(lArow, m, ks, cr, cl);
#pragma unroll
      for (int n = 0; n < 4; ++n) b[n] = ld_frag(lBrow, n, ks, cr, cl);
#pragma unroll
      for (int m = 0; m < 4; ++m)
#pragma unroll
        for (int n = 0; n < 4; ++n)
          acc[m][n] = __builtin_amdgcn_mfma_f32_16x16x32_bf16(a[m], b[n],
                                                              acc[m][n], 0, 0, 0);
    }
    __syncthreads();
  }

#pragma unroll
  for (int m = 0; m < 4; ++m) {
#pragma unroll
    for (int r = 0; r < 4; ++r) {
      const size_t row = row0 + wr * 64 + m * 16 + cr * 4 + r;
      const unsigned long long key = mink[row];
      const float d2 = __uint_as_float((unsigned int)(key >> 32));
      const bool usec = (d2 <= 1e-4f);
      const unsigned int idx = (unsigned int)(key & 0xFFFFFFFFu);
#pragma unroll
      for (int n = 0; n < 4; ++n) {
        const size_t col = col0 + wc * 64 + n * 16 + cl;
        float v = acc[m][n][r] + bias[col];
        if (usec) v = cache_out[(size_t)idx * KK + col];
        out[row * KK + col] = v;
      }
    }
  }
}

extern "C" void kernel_launch(void* const* d_in, const int* in_sizes, int n_in,
                              void* d_out, int out_size, void* d_ws,
                              size_t ws_size, hipStream_t stream) {
  const float* x = (const float*)d_in[0];
  const float* cache_emb = (const float*)d_in[1];
  const float* cache_out = (const float*)d_in[2];
  const float* W = (const float*)d_in[3];
  const float* bias = (const float*)d_in[4];
  float* out = (float*)d_out;
  char* ws = (char*)d_ws;

  unsigned long long* mink = (unsigned long long*)(ws + MIN_OFF);
  float* x2 = (float*)(ws + X2_OFF);
  float* c2 = (float*)(ws + C2_OFF);
  short* xb = (short*)(ws + XB_OFF);
  unsigned char* xq = (unsigned char*)(ws + XQ_OFF);
  unsigned char* cq = (unsigned char*)(ws + CQ_OFF);
  short* wt = (short*)(ws + WT_OFF);
  unsigned long long* part = (unsigned long long*)(ws + PART_OFF);

  hipMemsetAsync(part, 0xFF, (size_t)NQ * 64 * 8, stream);
  prep_rows<1, 7><<<NQ / 4, 256, 0, stream>>>(x, xb, xq, x2);
  prep_rows<0, 8><<<MC / 4, 256, 0, stream>>>(cache_emb, nullptr, cq, c2);
  prep_w<<<dim3(KK / 64, DD / 64), 256, 0, stream>>>(W, wt);
  gemm_min<<<(NQ / 128) * (MC / 256), 512, 0, stream>>>(xq, cq, x2, c2, part);
  reduce_mink<<<NQ / 256, 256, 0, stream>>>(part, mink);
  gemm_out<<<dim3(KK / 128, NQ / 128), 256, 0, stream>>>(xb, wt, bias,
                                                         cache_out, mink, out);
}

// Round 13
// 171.898 us; speedup vs baseline: 1.0266x; 1.0266x over previous
//
#include <hip/hip_runtime.h>
#include <hip/hip_bf16.h>
#include <hip/hip_fp8.h>
#include <cstdint>
#include <cstddef>

// out = where(min_dist(x, cache_emb) <= 0.01, cache_out[argmin], x@W+b)
// N=8192, M=16384, D=512, K=512, f32 in/out.
// gemm_min: non-scaled fp8 e4m3, 128x256 tile, 8 waves (2x4), kt-blocked
//   global layout, row-pair XOR swizzle (0 conflicts, R10-12-verified),
//   TRIPLE-buffered BK=64 pipeline -> ONE barrier per kt, vmcnt(3) with
//   2-phase latency headroom, 2 blocks/CU.
// gemm_out: bf16 (accuracy), unchanged.

#define NQ 8192
#define MC 16384
#define DD 512
#define KK 512

typedef float f32x4 __attribute__((ext_vector_type(4)));
typedef __bf16 bf16x8 __attribute__((ext_vector_type(8)));
typedef short short8 __attribute__((ext_vector_type(8)));

// ---- workspace layout (bytes) ----
#define MIN_OFF 0u
#define X2_OFF 65536u
#define C2_OFF 98304u
#define XB_OFF 163840u                          // bf16 x: 8 MB
#define XQ_OFF (XB_OFF + 8388608u)              // fp8 x (blocked, 128-panels): 4 MB
#define CQ_OFF (XQ_OFF + 4194304u)              // fp8 cache_emb (blocked, 256-panels): 8 MB
#define WT_OFF (CQ_OFF + 8388608u)              // bf16 W^T: 512 KB
#define PART_OFF (WT_OFF + 524288u)             // partial mins: 4 MB

__device__ __forceinline__ short f2bf(float f) {
  unsigned int u = __float_as_uint(f);
  u += 0x7FFFu + ((u >> 16) & 1u);
  return (short)(u >> 16);
}

__device__ __forceinline__ void gload_lds16(const void* g, void* l) {
  __builtin_amdgcn_global_load_lds(
      (__attribute__((address_space(1))) void*)(g),
      (__attribute__((address_space(3))) void*)(l), 16, 0, 0);
}

__device__ __forceinline__ unsigned long long u64min(unsigned long long a,
                                                     unsigned long long b) {
  return a < b ? a : b;
}

// ---- cast rows to fp8 (kt-blocked layout, panel of 2^PS rows) ----
// tile (panel=row>>PS, kt) is (2^PS * 64) B contiguous; row rl within it
// occupies 64 B; 8B group gl stored at gl ^ ((rl>>1)&7)  [row-pair swizzle].
template <int WRITE_BF16, int PS>
__global__ __launch_bounds__(256) void prep_rows(const float* __restrict__ src,
                                                 short* __restrict__ dstb,
                                                 unsigned char* __restrict__ dstq,
                                                 float* __restrict__ dst2) {
  const int lane = threadIdx.x & 63;
  const size_t row = (size_t)blockIdx.x * 4 + (threadIdx.x >> 6);
  const float4* p = (const float4*)(src + row * DD + lane * 8);
  float4 v0 = p[0], v1 = p[1];
  float v[8] = {v0.x, v0.y, v0.z, v0.w, v1.x, v1.y, v1.z, v1.w};
  unsigned long long pk = 0;
  float s = 0.f;
#pragma unroll
  for (int j = 0; j < 8; ++j) {
    __hip_fp8_e4m3 q(v[j]);
    float qf = (float)q;
    s += qf * qf;
    pk |= (unsigned long long)q.__x << (8 * j);
  }
  const int kt = lane >> 3, gl = lane & 7;
  const int rl = (int)row & ((1 << PS) - 1);
  const size_t panel = row >> PS;
  const size_t tile_bytes = (size_t)(1 << PS) * 64;
  *(unsigned long long*)(dstq + (panel * 8 + kt) * tile_bytes + rl * 64 +
                         ((gl ^ ((rl >> 1) & 7)) << 3)) = pk;
  if (WRITE_BF16) {
    short8 o;
#pragma unroll
    for (int j = 0; j < 8; ++j) o[j] = f2bf(v[j]);
    *(short8*)(dstb + row * DD + lane * 8) = o;
  }
#pragma unroll
  for (int m = 32; m >= 1; m >>= 1) s += __shfl_xor(s, m, 64);
  if (lane == 0) dst2[row] = s;
}

// ---- transpose-cast W[d][j] -> wt[j][d] (bf16) ----
__global__ __launch_bounds__(256) void prep_w(const float* __restrict__ W,
                                              short* __restrict__ wt) {
  __shared__ float t[64][65];
  const int bx = blockIdx.x, by = blockIdx.y;
#pragma unroll
  for (int i = 0; i < 16; ++i) {
    int idx = i * 256 + threadIdx.x;
    int r = idx >> 6, c = idx & 63;
    t[r][c] = W[(size_t)(by * 64 + r) * KK + bx * 64 + c];
  }
  __syncthreads();
#pragma unroll
  for (int i = 0; i < 16; ++i) {
    int idx = i * 256 + threadIdx.x;
    int r = idx >> 6, c = idx & 63;
    wt[(size_t)(bx * 64 + r) * DD + by * 64 + c] = f2bf(t[c][r]);
  }
}

// ======================= fp8 distance GEMM (3-buf pipelined) =================
// 128x256 tile, 8 waves (2x4 of 64x64). Triple-buffered BK=64, per kt:
// { vmcnt(3) ; barrier ; STAGE(kt+2 -> buf[(kt+2)%3]) ; ds_read+MFMA(buf[kt%3]) }.
// STAGE targets the buffer last read at kt-1; any wave past barrier kt implies
// all waves consumed their kt-1 reads -> safe with ONE barrier per kt.
// Frag slot (ks*4+cr)^((cl>>1)&7) -> 2-way bank alias (free).
__global__ __launch_bounds__(512, 4) void gemm_min(
    const unsigned char* __restrict__ xq, const unsigned char* __restrict__ cq,
    const float* __restrict__ x2, const float* __restrict__ c2,
    unsigned long long* __restrict__ part) {
  __shared__ unsigned char LA[3][8192];   // A: 128 x 64B
  __shared__ unsigned char LB[3][16384];  // B: 256 x 64B   (72 KiB total)
  const int tid = threadIdx.x;
  const int lane = tid & 63;
  const int wid = tid >> 6;
  const int wr = wid >> 2, wc = wid & 3;  // 2x4 wave grid, 64x64 each
  const int cl = lane & 15, cr = lane >> 4;

  // XCD mapping: per XCD 8 fixed A-panels; B walked in groups of 16.
  const int bid = blockIdx.x;                 // 0..4095
  const int xcd = bid & 7;
  const int k = bid >> 3;                     // 0..511
  const int by = xcd * 8 + ((k >> 4) & 7);    // 0..63 (128-row A panels)
  const int bx = ((k >> 7) << 4) | (k & 15);  // 0..63 (256-row B panels)
  const size_t row0 = (size_t)by * 128;
  const size_t col0 = (size_t)bx * 256;

  const unsigned char* tA = xq + (size_t)by * 65536;   // 8 tiles x 8192 B
  const unsigned char* tB = cq + (size_t)bx * 131072;  // 8 tiles x 16384 B

  f32x4 acc[4][4];
#pragma unroll
  for (int m = 0; m < 4; ++m)
#pragma unroll
    for (int n = 0; n < 4; ++n) acc[m][n] = (f32x4)0.0f;

#define STAGE(buf, kt)                                                   \
  do {                                                                   \
    gload_lds16(tA + (kt) * 8192 + tid * 16, &LA[buf][tid * 16]);        \
    gload_lds16(tB + (kt) * 16384 + tid * 16, &LB[buf][tid * 16]);       \
    gload_lds16(tB + (kt) * 16384 + 8192 + tid * 16,                     \
                &LB[buf][8192 + tid * 16]);                              \
  } while (0)

  STAGE(0, 0);
  STAGE(1, 1);  // 6 loads in flight
#pragma unroll
  for (int kt = 0; kt < 8; ++kt) {
    if (kt < 7) {
      // buf[kt%3]'s 3 loads were issued two phases ago; 3 newer outstanding.
      asm volatile("s_waitcnt vmcnt(3)" ::: "memory");
    } else {
      asm volatile("s_waitcnt vmcnt(0)" ::: "memory");
    }
    __builtin_amdgcn_s_barrier();        // all waves: buf[kt%3] staged
    __builtin_amdgcn_sched_barrier(0);   // pin reads below barrier (rule #18)
    if (kt < 6) STAGE((kt + 2) % 3, kt + 2);  // overwrites buf read at kt-1
    const unsigned char* lAr = &LA[kt % 3][(wr * 64 + cl) * 64];
    const unsigned char* lBr = &LB[kt % 3][(wc * 64 + cl) * 64];
#pragma unroll
    for (int ks = 0; ks < 2; ++ks) {
      const int sl = ((ks * 4 + cr) ^ ((cl >> 1) & 7)) << 3;
      long a[4], b[4];
#pragma unroll
      for (int m = 0; m < 4; ++m) a[m] = *(const long*)(lAr + m * 1024 + sl);
#pragma unroll
      for (int n = 0; n < 4; ++n) b[n] = *(const long*)(lBr + n * 1024 + sl);
#pragma unroll
      for (int m = 0; m < 4; ++m)
#pragma unroll
        for (int n = 0; n < 4; ++n)
          acc[m][n] = __builtin_amdgcn_mfma_f32_16x16x32_fp8_fp8(
              a[m], b[n], acc[m][n], 0, 0, 0);
    }
    // no trailing barrier: next STAGE targets a buffer sealed by barrier kt+1
  }
#undef STAGE

  // epilogue: d2 = x2 + c2 - 2S; pack (d2bits,col); 16-lane butterfly;
  // cross-wave LDS combine (4 col-waves); one atomicMin per row per block.
  // (ls = LA[0]: last read at kt=6, sealed by barrier 7.)
  unsigned long long* ls = (unsigned long long*)&LA[0][0];  // [128][4]
  float c2v[4];
#pragma unroll
  for (int n = 0; n < 4; ++n) c2v[n] = c2[col0 + wc * 64 + n * 16 + cl];
#pragma unroll
  for (int m = 0; m < 4; ++m) {
#pragma unroll
    for (int r = 0; r < 4; ++r) {
      const int row_local = wr * 64 + m * 16 + cr * 4 + r;
      const float xv = x2[row0 + row_local];
      unsigned long long best = ~0ull;
#pragma unroll
      for (int n = 0; n < 4; ++n) {
        float d2 = fmaxf(xv + c2v[n] - 2.0f * acc[m][n][r], 0.0f);
        unsigned int col = (unsigned int)(col0 + wc * 64 + n * 16 + cl);
        unsigned long long key =
            ((unsigned long long)__float_as_uint(d2) << 32) | col;
        best = u64min(best, key);
      }
#pragma unroll
      for (int msk = 8; msk >= 1; msk >>= 1) {
        unsigned long long o = __shfl_xor(best, msk, 64);
        best = u64min(best, o);
      }
      if (cl == 0) ls[row_local * 4 + wc] = best;
    }
  }
  __syncthreads();
  if (tid < 128) {
    unsigned long long b = u64min(u64min(ls[tid * 4 + 0], ls[tid * 4 + 1]),
                                  u64min(ls[tid * 4 + 2], ls[tid * 4 + 3]));
    atomicMin(&part[(size_t)(row0 + tid) * 64 + bx], b);
  }
}

// ---- final argmin reduce ----
__global__ __launch_bounds__(256) void reduce_mink(
    const unsigned long long* __restrict__ part,
    unsigned long long* __restrict__ mink) {
  const int row = blockIdx.x * 256 + threadIdx.x;
  const unsigned long long* p = part + (size_t)row * 64;
  unsigned long long best = ~0ull;
#pragma unroll
  for (int j = 0; j < 64; ++j) best = best < p[j] ? best : p[j];
  mink[row] = best;
}

// ======================= bf16 fallback GEMM (unchanged) ======================
__device__ __forceinline__ void stage_offs(unsigned go[4], size_t grow0,
                                           int wid, int lane) {
#pragma unroll
  for (int j = 0; j < 4; ++j) {
    const int ch = wid * 256 + j * 64 + lane;
    const int r = ch >> 3;
    const int c = (ch & 7) ^ (r & 7);
    go[j] = (unsigned)((grow0 + (size_t)r) * (DD * 2) + c * 16);
  }
}

__device__ __forceinline__ void stage_tile(const char* base,
                                           const unsigned go[4], unsigned kb,
                                           char* lds, int wid) {
#pragma unroll
  for (int j = 0; j < 4; ++j)
    gload_lds16(base + go[j] + kb, lds + (wid * 256 + j * 64) * 16);
}

__device__ __forceinline__ bf16x8 ld_frag(const short* lrow0, int m, int ks,
                                          int cr, int cl) {
  const int slot = (ks * 4 + cr) ^ (cl & 7);
  return *(const bf16x8*)(lrow0 + m * 16 * 64 + slot * 8);
}

__global__ __launch_bounds__(256, 3) void gemm_out(
    const short* __restrict__ xb, const short* __restrict__ wt,
    const float* __restrict__ bias, const float* __restrict__ cache_out,
    const unsigned long long* __restrict__ mink, float* __restrict__ out) {
  __shared__ short lA[128 * 64];
  __shared__ short lB[128 * 64];
  const int tid = threadIdx.x;
  const int lane = tid & 63;
  const int wid = tid >> 6;
  const int wr = wid >> 1, wc = wid & 1;
  const int cl = lane & 15, cr = lane >> 4;
  const size_t row0 = (size_t)blockIdx.y * 128;
  const size_t col0 = (size_t)blockIdx.x * 128;

  unsigned goA[4], goB[4];
  stage_offs(goA, row0, wid, lane);
  stage_offs(goB, col0, wid, lane);
  const char* xbp = (const char*)xb;
  const char* wtp = (const char*)wt;

  f32x4 acc[4][4];
#pragma unroll
  for (int m = 0; m < 4; ++m)
#pragma unroll
    for (int n = 0; n < 4; ++n) acc[m][n] = (f32x4)0.0f;

  const short* lArow = lA + (wr * 64 + cl) * 64;
  const short* lBrow = lB + (wc * 64 + cl) * 64;

  for (int kt = 0; kt < DD / 64; ++kt) {
    stage_tile(xbp, goA, (unsigned)kt * 128, (char*)lA, wid);
    stage_tile(wtp, goB, (unsigned)kt * 128, (char*)lB, wid);
    __syncthreads();
#pragma unroll
    for (int ks = 0; ks < 2; ++ks) {
      bf16x8 a[4], b[4];
#pragma unroll
      for (int m = 0; m < 4; ++m) a[m] = ld_frag(lArow, m, ks, cr, cl);
#pragma unroll
      for (int n = 0; n < 4; ++n) b[n] = ld_frag(lBrow, n, ks, cr, cl);
#pragma unroll
      for (int m = 0; m < 4; ++m)
#pragma unroll
        for (int n = 0; n < 4; ++n)
          acc[m][n] = __builtin_amdgcn_mfma_f32_16x16x32_bf16(a[m], b[n],
                                                              acc[m][n], 0, 0, 0);
    }
    __syncthreads();
  }

#pragma unroll
  for (int m = 0; m < 4; ++m) {
#pragma unroll
    for (int r = 0; r < 4; ++r) {
      const size_t row = row0 + wr * 64 + m * 16 + cr * 4 + r;
      const unsigned long long key = mink[row];
      const float d2 = __uint_as_float((unsigned int)(key >> 32));
      const bool usec = (d2 <= 1e-4f);
      const unsigned int idx = (unsigned int)(key & 0xFFFFFFFFu);
#pragma unroll
      for (int n = 0; n < 4; ++n) {
        const size_t col = col0 + wc * 64 + n * 16 + cl;
        float v = acc[m][n][r] + bias[col];
        if (usec) v = cache_out[(size_t)idx * KK + col];
        out[row * KK + col] = v;
      }
    }
  }
}

extern "C" void kernel_launch(void* const* d_in, const int* in_sizes, int n_in,
                              void* d_out, int out_size, void* d_ws,
                              size_t ws_size, hipStream_t stream) {
  const float* x = (const float*)d_in[0];
  const float* cache_emb = (const float*)d_in[1];
  const float* cache_out = (const float*)d_in[2];
  const float* W = (const float*)d_in[3];
  const float* bias = (const float*)d_in[4];
  float* out = (float*)d_out;
  char* ws = (char*)d_ws;

  unsigned long long* mink = (unsigned long long*)(ws + MIN_OFF);
  float* x2 = (float*)(ws + X2_OFF);
  float* c2 = (float*)(ws + C2_OFF);
  short* xb = (short*)(ws + XB_OFF);
  unsigned char* xq = (unsigned char*)(ws + XQ_OFF);
  unsigned char* cq = (unsigned char*)(ws + CQ_OFF);
  short* wt = (short*)(ws + WT_OFF);
  unsigned long long* part = (unsigned long long*)(ws + PART_OFF);

  hipMemsetAsync(part, 0xFF, (size_t)NQ * 64 * 8, stream);
  prep_rows<1, 7><<<NQ / 4, 256, 0, stream>>>(x, xb, xq, x2);
  prep_rows<0, 8><<<MC / 4, 256, 0, stream>>>(cache_emb, nullptr, cq, c2);
  prep_w<<<dim3(KK / 64, DD / 64), 256, 0, stream>>>(W, wt);
  gemm_min<<<(NQ / 128) * (MC / 256), 512, 0, stream>>>(xq, cq, x2, c2, part);
  reduce_mink<<<NQ / 256, 256, 0, stream>>>(part, mink);
  gemm_out<<<dim3(KK / 128, NQ / 128), 256, 0, stream>>>(xb, wt, bias,
                                                         cache_out, mink, out);
}